// Round 2
// baseline (554.093 us; speedup 1.0000x reference)
//
#include <hip/hip_runtime.h>

// SABlock: x(4,512,64,64) -> phi/theta/g (1x1 convs, CI=256) -> f=theta^T@phi
// -> softmax -> y=a@g^T -> w_mask 1x1 conv -> out(4,512,64,64)
// All GEMMs fp16-in / fp32-accumulate on MFMA 16x16x32_f16.
// Round 2: flash rebuilt — 32 q-rows/wave + 2-way kv split, Q in regs,
// phi/g streamed global->VGPR (L2-resident per XCD), conflict-free P LDS
// round-trip, 2 barriers/step (stats exchange only).

#define BB 4
#define CC 512
#define NN_SP 4096   // H*W
#define CI 256

typedef _Float16 f16x8 __attribute__((ext_vector_type(8)));
typedef float f32x4 __attribute__((ext_vector_type(4)));

__device__ __forceinline__ void async16(const void* gsrc, void* ldst) {
  __builtin_amdgcn_global_load_lds(
      (const __attribute__((address_space(1))) unsigned int*)gsrc,
      (__attribute__((address_space(3))) unsigned int*)ldst, 16, 0, 0);
}

// ---------------- weight convert: fp32 -> f16, stack [w_phi; w_theta] ----------------
__global__ __launch_bounds__(256) void convert_w(
    const float* __restrict__ wphi, const float* __restrict__ wtheta,
    const float* __restrict__ wg, const float* __restrict__ wmask,
    _Float16* __restrict__ wpt, _Float16* __restrict__ wgh, _Float16* __restrict__ wmh) {
  int i = blockIdx.x * 256 + threadIdx.x;
  if (i < 512 * 512) {                       // wpt rows: 0..255 phi, 256..511 theta
    int row = i >> 9, k = i & 511;
    float v = (row < 256) ? wphi[row * 512 + k] : wtheta[(row - 256) * 512 + k];
    wpt[i] = (_Float16)v;
  } else if (i < 512 * 512 + 256 * 512) {
    int j = i - 512 * 512;
    wgh[j] = (_Float16)wg[j];
  } else {
    int j = i - 512 * 512 - 256 * 512;
    wmh[j] = (_Float16)wmask[j];
  }
}

// ---------------- x (B,512,4096) fp32 -> x_T (B,4096,512) f16 ----------------
__global__ __launch_bounds__(256) void transpose_x(const float* __restrict__ x,
                                                   _Float16* __restrict__ xT) {
  __shared__ float tile[64][65];   // +1 pad: conflict-free column read
  const int n0 = blockIdx.x * 64, c0 = blockIdx.y * 64, b = blockIdx.z;
  const int tx = threadIdx.x & 63, ty = threadIdx.x >> 6;
  const float* xb = x + (long long)b * CC * NN_SP;
#pragma unroll
  for (int i = 0; i < 16; ++i) {
    int row = i * 4 + ty;
    tile[row][tx] = xb[(long long)(c0 + row) * NN_SP + n0 + tx];
  }
  __syncthreads();
  _Float16* xTb = xT + (long long)b * NN_SP * CC;
#pragma unroll
  for (int i = 0; i < 16; ++i) {
    int row = i * 4 + ty;
    xTb[(long long)(n0 + row) * CC + c0 + tx] = (_Float16)tile[tx][row];
  }
}

// ---------------- generic gemm_bt: C[m,n] = sum_k A[m,k] * Bt[n,k] ----------------
// m97 structure: global_load_lds width-16 staging, 4 waves 2x2, 16 MFMA/wave/K-step.
template <int M, int NT, int K, bool F16OUT>
__global__ __launch_bounds__(256, 2) void gemm_bt(
    const _Float16* __restrict__ Ab, const _Float16* __restrict__ Btb,
    void* __restrict__ Cb, long long sA, long long sB, long long sC) {
  __shared__ _Float16 As[128 * 32];
  __shared__ _Float16 Bs[128 * 32];
  const int tid = threadIdx.x, lane = tid & 63, w = tid >> 6;
  const int wm = w >> 1, wn = w & 1;
  const int l15 = lane & 15, lq = lane >> 4;
  const int b = blockIdx.z;
  const _Float16* A = Ab + (long long)b * sA;
  const _Float16* Bt = Btb + (long long)b * sB;
  const int m0 = blockIdx.y * 128, n0 = blockIdx.x * 128;

  f32x4 acc[4][4];
#pragma unroll
  for (int i = 0; i < 4; ++i)
#pragma unroll
    for (int j = 0; j < 4; ++j) acc[i][j] = (f32x4){0.f, 0.f, 0.f, 0.f};

  for (int k0 = 0; k0 < K; k0 += 32) {
    __syncthreads();  // previous LDS reads done before overwrite
#pragma unroll
    for (int j = 0; j < 2; ++j) {
      int chw = j * 256 + w * 64;      // wave-uniform chunk base
      int ch = chw + lane;
      int row = ch >> 2, kc = ch & 3;  // 4 x 16B chunks per 32-k row segment
      async16(A + (long long)(m0 + row) * K + k0 + kc * 8, (void*)(As + chw * 8));
      async16(Bt + (long long)(n0 + row) * K + k0 + kc * 8, (void*)(Bs + chw * 8));
    }
    __syncthreads();  // vmcnt(0) drain + barrier
    f16x8 af[4], bf[4];
#pragma unroll
    for (int mt = 0; mt < 4; ++mt)
      af[mt] = *(const f16x8*)(As + (wm * 64 + mt * 16 + l15) * 32 + lq * 8);
#pragma unroll
    for (int nt = 0; nt < 4; ++nt)
      bf[nt] = *(const f16x8*)(Bs + (wn * 64 + nt * 16 + l15) * 32 + lq * 8);
#pragma unroll
    for (int mt = 0; mt < 4; ++mt)
#pragma unroll
      for (int nt = 0; nt < 4; ++nt)
        acc[mt][nt] = __builtin_amdgcn_mfma_f32_16x16x32_f16(af[mt], bf[nt], acc[mt][nt], 0, 0, 0);
  }

#pragma unroll
  for (int mt = 0; mt < 4; ++mt)
#pragma unroll
    for (int nt = 0; nt < 4; ++nt)
#pragma unroll
      for (int r = 0; r < 4; ++r) {
        int row = m0 + wm * 64 + mt * 16 + lq * 4 + r;  // C/D: row=(lane>>4)*4+reg
        int col = n0 + wn * 64 + nt * 16 + l15;         //      col=lane&15
        if (F16OUT)
          ((_Float16*)Cb + (long long)b * sC)[(long long)row * NT + col] = (_Float16)acc[mt][nt][r];
        else
          ((float*)Cb + (long long)b * sC)[(long long)row * NT + col] = acc[mt][nt][r];
      }
}

// ---------------- flash attention v2 ----------------
// pt (B,4096,512): cols 0..255 = phi_T, 256..511 = theta_T (c-contiguous)
// g  (B,256,4096): kv-contiguous.  yT (B,4096,256) f16 out.
// Block = 64 q-rows, 4 waves = (wq in {0,1} owns 32 q-rows) x (wk in {0,1} owns
// 64-kv half of each 128 step). Q in regs; phi/g streamed global->VGPR;
// per-wave partial y accumulated across all steps, combined in epilogue.
__global__ __launch_bounds__(256, 1) void flash_attn2(
    const _Float16* __restrict__ pt, const _Float16* __restrict__ g,
    _Float16* __restrict__ yT) {
  __shared__ _Float16 Ps[4][2048];   // per-wave P [32q][64kv], A-frag order (16 KB)
  __shared__ float StatM[2][2][32];
  __shared__ float StatL[2][2][32];
  __shared__ float EpS[8192];        // epilogue exchange (32 KB)

  const int tid = threadIdx.x, lane = tid & 63, w = tid >> 6;
  const int wq = w >> 1, wk = w & 1;
  const int l15 = lane & 15, lq = lane >> 4;

  // XCD-aware swizzle (assumes XCD = blockIdx % 8): 2 XCDs per batch so the
  // 4 MB phi+g working set of a batch stays L2-resident. Perf-only heuristic.
  const int idx = blockIdx.x;
  const int b = (idx >> 1) & 3;
  const int q0 = (((idx >> 3) << 1) | (idx & 1)) * 64;

  const _Float16* __restrict__ ptb = pt + (long long)b * NN_SP * 512;
  const _Float16* __restrict__ gb = g + (long long)b * CI * NN_SP;

  // Q (theta) resident in registers: 2 m-tiles x 8 k-chunks of 32 ch
  f16x8 qreg[2][8];
#pragma unroll
  for (int mt = 0; mt < 2; ++mt)
#pragma unroll
    for (int kk = 0; kk < 8; ++kk)
      qreg[mt][kk] = *(const f16x8*)(
          ptb + (long long)(q0 + wq * 32 + mt * 16 + l15) * 512 + 256 + kk * 32 + lq * 8);

  f32x4 yacc[2][16];
#pragma unroll
  for (int mt = 0; mt < 2; ++mt)
#pragma unroll
    for (int nt = 0; nt < 16; ++nt) yacc[mt][nt] = (f32x4){0.f, 0.f, 0.f, 0.f};
  float mrow[2][4], lrow[2][4];
#pragma unroll
  for (int mt = 0; mt < 2; ++mt)
#pragma unroll
    for (int r = 0; r < 4; ++r) { mrow[mt][r] = -3e38f; lrow[mt][r] = 0.f; }

  for (int t = 0; t < 32; ++t) {
    const int kvb = t * 128 + wk * 64;  // this wave's 64-kv slice

    // ---- S = theta @ phi^T (32q x 64kv), K=256, B-frags streamed from L2 ----
    f32x4 S[2][4];
#pragma unroll
    for (int mt = 0; mt < 2; ++mt)
#pragma unroll
      for (int nv = 0; nv < 4; ++nv) S[mt][nv] = (f32x4){0.f, 0.f, 0.f, 0.f};
#pragma unroll
    for (int kk = 0; kk < 8; ++kk) {
      f16x8 bf[4];
#pragma unroll
      for (int nv = 0; nv < 4; ++nv)
        bf[nv] = *(const f16x8*)(
            ptb + (long long)(kvb + nv * 16 + l15) * 512 + kk * 32 + lq * 8);
#pragma unroll
      for (int nv = 0; nv < 4; ++nv) {
        S[0][nv] = __builtin_amdgcn_mfma_f32_16x16x32_f16(qreg[0][kk], bf[nv], S[0][nv], 0, 0, 0);
        S[1][nv] = __builtin_amdgcn_mfma_f32_16x16x32_f16(qreg[1][kk], bf[nv], S[1][nv], 0, 0, 0);
      }
    }

    // ---- own partial row-max (over 4 nv tiles and 16 col-lanes) ----
    float pmx[2][4];
#pragma unroll
    for (int mt = 0; mt < 2; ++mt)
#pragma unroll
      for (int r = 0; r < 4; ++r) {
        float mx = fmaxf(fmaxf(S[mt][0][r], S[mt][1][r]), fmaxf(S[mt][2][r], S[mt][3][r]));
#pragma unroll
        for (int d = 1; d < 16; d <<= 1) mx = fmaxf(mx, __shfl_xor(mx, d, 64));
        pmx[mt][r] = mx;
      }
    if (l15 == 0) {
#pragma unroll
      for (int mt = 0; mt < 2; ++mt)
#pragma unroll
        for (int r = 0; r < 4; ++r) StatM[wq][wk][mt * 16 + lq * 4 + r] = pmx[mt][r];
    }
    __syncthreads();  // #A: StatM visible

    // ---- merge max with wk partner, exp, own partial sums ----
    float alpha[2][4], psum[2][4];
#pragma unroll
    for (int mt = 0; mt < 2; ++mt)
#pragma unroll
      for (int r = 0; r < 4; ++r) {
        float om = StatM[wq][wk ^ 1][mt * 16 + lq * 4 + r];
        float nm = fmaxf(mrow[mt][r], fmaxf(pmx[mt][r], om));
        alpha[mt][r] = __expf(mrow[mt][r] - nm);
        mrow[mt][r] = nm;
        float ps = 0.f;
#pragma unroll
        for (int nv = 0; nv < 4; ++nv) {
          float p = __expf(S[mt][nv][r] - nm);
          S[mt][nv][r] = p;
          ps += p;
        }
#pragma unroll
        for (int d = 1; d < 16; d <<= 1) ps += __shfl_xor(ps, d, 64);
        psum[mt][r] = ps;
      }
    if (l15 == 0) {
#pragma unroll
      for (int mt = 0; mt < 2; ++mt)
#pragma unroll
        for (int r = 0; r < 4; ++r) StatL[wq][wk][mt * 16 + lq * 4 + r] = psum[mt][r];
    }
    __syncthreads();  // #B: StatL visible

#pragma unroll
    for (int mt = 0; mt < 2; ++mt)
#pragma unroll
      for (int r = 0; r < 4; ++r) {
        float ol = StatL[wq][wk ^ 1][mt * 16 + lq * 4 + r];
        lrow[mt][r] = lrow[mt][r] * alpha[mt][r] + psum[mt][r] + ol;
      }
    // rescale partial y
#pragma unroll
    for (int mt = 0; mt < 2; ++mt) {
      f32x4 al = {alpha[mt][0], alpha[mt][1], alpha[mt][2], alpha[mt][3]};
#pragma unroll
      for (int nt = 0; nt < 16; ++nt) yacc[mt][nt] *= al;
    }

    // ---- P: C/D regs -> private LDS region in exact A-frag order ----
#pragma unroll
    for (int mt = 0; mt < 2; ++mt)
#pragma unroll
      for (int nv = 0; nv < 4; ++nv)
#pragma unroll
        for (int r = 0; r < 4; ++r) {
          int l15a = lq * 4 + r;                 // A row within 16-tile
          int lqa = (nv & 1) * 2 + (l15 >> 3);   // A k-chunk
          int e = l15 & 7;                       // element within chunk
          int unit = mt * 128 + (nv >> 1) * 64 + lqa * 16 + l15a;
          Ps[w][unit * 8 + e] = (_Float16)S[mt][nv][r];
        }

    // ---- y += P @ g^T, g B-frags streamed from L2, lane-contiguous Ps reads ----
#pragma unroll
    for (int km2 = 0; km2 < 2; ++km2) {
      f16x8 a0 = *(const f16x8*)(&Ps[w][(0 * 128 + km2 * 64 + lane) * 8]);
      f16x8 a1 = *(const f16x8*)(&Ps[w][(1 * 128 + km2 * 64 + lane) * 8]);
#pragma unroll
      for (int nt = 0; nt < 16; ++nt) {
        f16x8 bg = *(const f16x8*)(
            gb + (long long)(nt * 16 + l15) * 4096 + kvb + km2 * 32 + lq * 8);
        yacc[0][nt] = __builtin_amdgcn_mfma_f32_16x16x32_f16(a0, bg, yacc[0][nt], 0, 0, 0);
        yacc[1][nt] = __builtin_amdgcn_mfma_f32_16x16x32_f16(a1, bg, yacc[1][nt], 0, 0, 0);
      }
    }
  }

  // ---- epilogue: combine wk pair, divide by l, store yT ----
  _Float16* yTb = yT + (long long)b * NN_SP * CI;
#pragma unroll
  for (int mt = 0; mt < 2; ++mt) {
    __syncthreads();
    if (wk == 1) {
#pragma unroll
      for (int nt = 0; nt < 16; ++nt)
        *(f32x4*)(&EpS[(wq * 1024 + nt * 64 + lane) * 4]) = yacc[mt][nt];
    }
    __syncthreads();
    if (wk == 0) {
#pragma unroll
      for (int nt = 0; nt < 16; ++nt) {
        f32x4 o = yacc[mt][nt] + *(const f32x4*)(&EpS[(wq * 1024 + nt * 64 + lane) * 4]);
#pragma unroll
        for (int r = 0; r < 4; ++r) {
          int row = q0 + wq * 32 + mt * 16 + lq * 4 + r;
          yTb[(long long)row * CI + nt * 16 + l15] = (_Float16)(o[r] / lrow[mt][r]);
        }
      }
    }
  }
}

extern "C" void kernel_launch(void* const* d_in, const int* in_sizes, int n_in,
                              void* d_out, int out_size, void* d_ws, size_t ws_size,
                              hipStream_t stream) {
  const float* x = (const float*)d_in[0];
  const float* w_phi = (const float*)d_in[1];
  const float* w_theta = (const float*)d_in[2];
  const float* w_g = (const float*)d_in[3];
  const float* w_mask = (const float*)d_in[4];
  float* out = (float*)d_out;
  char* ws = (char*)d_ws;

  // workspace layout (51.4 MB total)
  _Float16* xT = (_Float16*)(ws);                 // (B,4096,512)  16.78 MB
  _Float16* pt = (_Float16*)(ws + 16777216);      // (B,4096,512)  16.78 MB  [phi|theta]
  _Float16* gB = (_Float16*)(ws + 33554432);      // (B,256,4096)   8.39 MB
  _Float16* yT = (_Float16*)(ws + 41943040);      // (B,4096,256)   8.39 MB
  _Float16* wpt = (_Float16*)(ws + 50331648);     // (512,512)
  _Float16* wg = (_Float16*)(ws + 50855936);      // (256,512)
  _Float16* wm = (_Float16*)(ws + 51118080);      // (512,256)

  convert_w<<<2048, 256, 0, stream>>>(w_phi, w_theta, w_g, w_mask, wpt, wg, wm);
  transpose_x<<<dim3(64, 8, 4), 256, 0, stream>>>(x, xT);
  // PT[n, {phi|theta}] = xT @ wpt^T : M=4096, N=512, K=512, per batch
  gemm_bt<4096, 512, 512, true><<<dim3(4, 32, 4), 256, 0, stream>>>(
      xT, wpt, pt, 4096LL * 512, 0, 4096LL * 512);
  // g[c, n] = wg @ x : M=256, N=4096, K=512 (Bt = xT), per batch
  gemm_bt<256, 4096, 512, true><<<dim3(32, 2, 4), 256, 0, stream>>>(
      wg, xT, gB, 0, 4096LL * 512, 256LL * 4096);
  // flash attention v2: 256 blocks (1/CU), XCD-swizzled
  flash_attn2<<<dim3(256), 256, 0, stream>>>(pt, gB, yT);
  // out[o, n] = wm @ y : M=512, N=4096, K=256 (Bt = yT), fp32 out, per batch
  gemm_bt<512, 4096, 256, false><<<dim3(32, 4, 4), 256, 0, stream>>>(
      wm, yT, out, 0, 4096LL * 256, 512LL * 4096);
}

// Round 3
// 356.530 us; speedup vs baseline: 1.5541x; 1.5541x over previous
//
#include <hip/hip_runtime.h>

// SABlock: x(4,512,64,64) -> phi/theta/g (1x1 convs, CI=256) -> f=theta^T@phi
// -> softmax -> y=a@g^T -> w_mask 1x1 conv -> out(4,512,64,64)
// All GEMMs fp16-in / fp32-accumulate on MFMA 16x16x32_f16.
// Round 3 flash: shared cooperative staging (4-wave amortized) in MFMA
// frag-order (conflict-free b128 reads), 3-buffer ring with raw
// s_barrier + s_waitcnt vmcnt(4) (loads stay in flight across barriers),
// wave-private online softmax (16 q-rows/wave, no stats barriers).

#define BB 4
#define CC 512
#define NN_SP 4096   // H*W
#define CI 256

typedef _Float16 f16x8 __attribute__((ext_vector_type(8)));
typedef float f32x4 __attribute__((ext_vector_type(4)));

__device__ __forceinline__ void async16(const void* gsrc, void* ldst) {
  __builtin_amdgcn_global_load_lds(
      (const __attribute__((address_space(1))) unsigned int*)gsrc,
      (__attribute__((address_space(3))) unsigned int*)ldst, 16, 0, 0);
}

// ---------------- weight convert: fp32 -> f16, stack [w_phi; w_theta] ----------------
__global__ __launch_bounds__(256) void convert_w(
    const float* __restrict__ wphi, const float* __restrict__ wtheta,
    const float* __restrict__ wg, const float* __restrict__ wmask,
    _Float16* __restrict__ wpt, _Float16* __restrict__ wgh, _Float16* __restrict__ wmh) {
  int i = blockIdx.x * 256 + threadIdx.x;
  if (i < 512 * 512) {                       // wpt rows: 0..255 phi, 256..511 theta
    int row = i >> 9, k = i & 511;
    float v = (row < 256) ? wphi[row * 512 + k] : wtheta[(row - 256) * 512 + k];
    wpt[i] = (_Float16)v;
  } else if (i < 512 * 512 + 256 * 512) {
    int j = i - 512 * 512;
    wgh[j] = (_Float16)wg[j];
  } else {
    int j = i - 512 * 512 - 256 * 512;
    wmh[j] = (_Float16)wmask[j];
  }
}

// ---------------- x (B,512,4096) fp32 -> x_T (B,4096,512) f16 ----------------
__global__ __launch_bounds__(256) void transpose_x(const float* __restrict__ x,
                                                   _Float16* __restrict__ xT) {
  __shared__ float tile[64][65];   // +1 pad: conflict-free column read
  const int n0 = blockIdx.x * 64, c0 = blockIdx.y * 64, b = blockIdx.z;
  const int tx = threadIdx.x & 63, ty = threadIdx.x >> 6;
  const float* xb = x + (long long)b * CC * NN_SP;
#pragma unroll
  for (int i = 0; i < 16; ++i) {
    int row = i * 4 + ty;
    tile[row][tx] = xb[(long long)(c0 + row) * NN_SP + n0 + tx];
  }
  __syncthreads();
  _Float16* xTb = xT + (long long)b * NN_SP * CC;
#pragma unroll
  for (int i = 0; i < 16; ++i) {
    int row = i * 4 + ty;
    xTb[(long long)(n0 + row) * CC + c0 + tx] = (_Float16)tile[tx][row];
  }
}

// ---------------- generic gemm_bt: C[m,n] = sum_k A[m,k] * Bt[n,k] ----------------
// m97 structure: global_load_lds width-16 staging, 4 waves 2x2, 16 MFMA/wave/K-step.
template <int M, int NT, int K, bool F16OUT>
__global__ __launch_bounds__(256, 2) void gemm_bt(
    const _Float16* __restrict__ Ab, const _Float16* __restrict__ Btb,
    void* __restrict__ Cb, long long sA, long long sB, long long sC) {
  __shared__ _Float16 As[128 * 32];
  __shared__ _Float16 Bs[128 * 32];
  const int tid = threadIdx.x, lane = tid & 63, w = tid >> 6;
  const int wm = w >> 1, wn = w & 1;
  const int l15 = lane & 15, lq = lane >> 4;
  const int b = blockIdx.z;
  const _Float16* A = Ab + (long long)b * sA;
  const _Float16* Bt = Btb + (long long)b * sB;
  const int m0 = blockIdx.y * 128, n0 = blockIdx.x * 128;

  f32x4 acc[4][4];
#pragma unroll
  for (int i = 0; i < 4; ++i)
#pragma unroll
    for (int j = 0; j < 4; ++j) acc[i][j] = (f32x4){0.f, 0.f, 0.f, 0.f};

  for (int k0 = 0; k0 < K; k0 += 32) {
    __syncthreads();  // previous LDS reads done before overwrite
#pragma unroll
    for (int j = 0; j < 2; ++j) {
      int chw = j * 256 + w * 64;      // wave-uniform chunk base
      int ch = chw + lane;
      int row = ch >> 2, kc = ch & 3;  // 4 x 16B chunks per 32-k row segment
      async16(A + (long long)(m0 + row) * K + k0 + kc * 8, (void*)(As + chw * 8));
      async16(Bt + (long long)(n0 + row) * K + k0 + kc * 8, (void*)(Bs + chw * 8));
    }
    __syncthreads();  // vmcnt(0) drain + barrier
    f16x8 af[4], bf[4];
#pragma unroll
    for (int mt = 0; mt < 4; ++mt)
      af[mt] = *(const f16x8*)(As + (wm * 64 + mt * 16 + l15) * 32 + lq * 8);
#pragma unroll
    for (int nt = 0; nt < 4; ++nt)
      bf[nt] = *(const f16x8*)(Bs + (wn * 64 + nt * 16 + l15) * 32 + lq * 8);
#pragma unroll
    for (int mt = 0; mt < 4; ++mt)
#pragma unroll
      for (int nt = 0; nt < 4; ++nt)
        acc[mt][nt] = __builtin_amdgcn_mfma_f32_16x16x32_f16(af[mt], bf[nt], acc[mt][nt], 0, 0, 0);
  }

#pragma unroll
  for (int mt = 0; mt < 4; ++mt)
#pragma unroll
    for (int nt = 0; nt < 4; ++nt)
#pragma unroll
      for (int r = 0; r < 4; ++r) {
        int row = m0 + wm * 64 + mt * 16 + lq * 4 + r;  // C/D: row=(lane>>4)*4+reg
        int col = n0 + wn * 64 + nt * 16 + l15;         //      col=lane&15
        if (F16OUT)
          ((_Float16*)Cb + (long long)b * sC)[(long long)row * NT + col] = (_Float16)acc[mt][nt][r];
        else
          ((float*)Cb + (long long)b * sC)[(long long)row * NT + col] = acc[mt][nt][r];
      }
}

// ---------------- flash attention v3 ----------------
// pt (B,4096,512): cols 0..255 = phi_T, 256..511 = theta_T (c-contiguous)
// g  (B,256,4096): kv-contiguous.  yT (B,4096,256) f16 out.
// Block = 64 q-rows, 4 waves, each wave owns 16 q-rows (wave-private softmax
// stats). Per 128-kv step: 8 staging phases (4 phi 16KB + 4 g 16KB) into a
// 3-buffer ring, prefetch depth 2. Raw s_barrier + vmcnt(4): the current
// phase's 4 wave-issues drain, the 8 prefetched ones stay in flight.
// Staging is permuted so the LDS image is in MFMA B-frag order: every frag
// read is a lane-contiguous ds_read_b128 over 1KB => zero bank conflicts.
__global__ __launch_bounds__(256) void flash_attn3(
    const _Float16* __restrict__ pt, const _Float16* __restrict__ g,
    _Float16* __restrict__ yT) {
  __shared__ _Float16 Stg[3][8192];  // 3 x 16KB ring
  __shared__ _Float16 Ps[4][2048];   // per-wave P [16q][128kv] in A-frag order (16KB)
  const int tid = threadIdx.x, lane = tid & 63, w = tid >> 6;
  const int l15 = lane & 15, lq = lane >> 4;

  // XCD swizzle: 2 XCDs per batch -> per-XCD L2 working set = one batch's 4MB
  const int idx = blockIdx.x;
  const int b = (idx >> 1) & 3;
  const int q0 = (((idx >> 3) << 1) | (idx & 1)) * 64;
  const _Float16* __restrict__ ptb = pt + (long long)b * NN_SP * 512;
  const _Float16* __restrict__ gb = g + (long long)b * CI * NN_SP;

  // Per-issue lane offsets (frag-order permutation), invariant over phases.
  // phi chunk [128kv][64ch]: unit u -> (k2=u>>9, nv=(u>>6)&7, r15=(u>>2)&15, rq=u&3)
  //   src elem = (kv0 + nv*16 + r15)*512 + (c*64 + k2*32 + rq*8)
  // g chunk [64c][128kv]: unit u -> (kq=u>>8, ct=(u>>6)&3, r15, rq)
  //   src elem = (c0 + ct*16 + r15)*4096 + (kv0 + kq*32 + rq*8)
  int offPhi[4], offG[4], chw_[4];
#pragma unroll
  for (int j = 0; j < 4; ++j) {
    int u = w * 256 + j * 64 + lane;
    chw_[j] = w * 256 + j * 64;
    int k2 = u >> 9, nv8 = (u >> 6) & 7, r15 = (u >> 2) & 15, rq = u & 3;
    offPhi[j] = (nv8 * 16 + r15) * 512 + k2 * 32 + rq * 8;
    int kq = u >> 8, ct4 = (u >> 6) & 3;
    offG[j] = (ct4 * 16 + r15) * 4096 + kq * 32 + rq * 8;
  }

  // Q (theta) resident in registers: 16 q-rows, 8 k-chunks of 32 ch
  f16x8 qreg[8];
#pragma unroll
  for (int kk = 0; kk < 8; ++kk)
    qreg[kk] = *(const f16x8*)(
        ptb + (long long)(q0 + w * 16 + l15) * 512 + 256 + kk * 32 + lq * 8);

  f32x4 yacc[16];
#pragma unroll
  for (int nt = 0; nt < 16; ++nt) yacc[nt] = (f32x4){0.f, 0.f, 0.f, 0.f};
  float mrow[4] = {-3e38f, -3e38f, -3e38f, -3e38f};
  float lrow[4] = {0.f, 0.f, 0.f, 0.f};

  // issue phase q into buffer bi (4 async16 per wave = 4 vm ops)
  auto issue = [&](int q, int bi) {
    if (q >= 256) return;
    _Float16* buf = Stg[bi];
    int tq = q >> 3, sub = q & 7, kv0 = tq * 128;
    if (sub < 4) {
      const _Float16* basep = ptb + kv0 * 512 + sub * 64;
#pragma unroll
      for (int j = 0; j < 4; ++j)
        async16(basep + offPhi[j], (void*)(buf + chw_[j] * 8));
    } else {
      const _Float16* baseg = gb + (sub - 4) * 64 * 4096 + kv0;
#pragma unroll
      for (int j = 0; j < 4; ++j)
        async16(baseg + offG[j], (void*)(buf + chw_[j] * 8));
    }
  };

  int p = 0, bcur = 0;     // phase counter, ring position (p % 3)
  issue(0, 0);
  issue(1, 1);

  for (int t = 0; t < 32; ++t) {
    f32x4 S[8];
#pragma unroll
    for (int i = 0; i < 8; ++i) S[i] = (f32x4){0.f, 0.f, 0.f, 0.f};

    // ---- 4 phi phases: S = theta @ phi^T ----
#pragma unroll
    for (int c = 0; c < 4; ++c) {
      asm volatile("s_waitcnt vmcnt(4)" ::: "memory");  // phase p's loads done
      asm volatile("s_barrier" ::: "memory");           // all waves: data in, prev buf free
      int bn = bcur + 2; if (bn >= 3) bn -= 3;
      issue(p + 2, bn);
      const _Float16* buf = Stg[bcur];
#pragma unroll
      for (int k2 = 0; k2 < 2; ++k2)
#pragma unroll
        for (int nv = 0; nv < 8; ++nv) {
          f16x8 bf = *(const f16x8*)(buf + (k2 * 512 + nv * 64 + l15 * 4 + lq) * 8);
          S[nv] = __builtin_amdgcn_mfma_f32_16x16x32_f16(qreg[c * 2 + k2], bf, S[nv], 0, 0, 0);
        }
      ++p; ++bcur; if (bcur == 3) bcur = 0;
    }

    // ---- wave-private online softmax (rows = lq*4+r, cols across l15) ----
    float alpha[4];
#pragma unroll
    for (int r = 0; r < 4; ++r) {
      float mx = fmaxf(fmaxf(S[0][r], S[1][r]), fmaxf(S[2][r], S[3][r]));
      mx = fmaxf(mx, fmaxf(fmaxf(S[4][r], S[5][r]), fmaxf(S[6][r], S[7][r])));
#pragma unroll
      for (int d = 1; d < 16; d <<= 1) mx = fmaxf(mx, __shfl_xor(mx, d, 64));
      float nm = fmaxf(mrow[r], mx);
      alpha[r] = __expf(mrow[r] - nm);
      mrow[r] = nm;
      float ps = 0.f;
#pragma unroll
      for (int nv = 0; nv < 8; ++nv) {
        float pv = __expf(S[nv][r] - nm);
        S[nv][r] = pv;
        ps += pv;
      }
#pragma unroll
      for (int d = 1; d < 16; d <<= 1) ps += __shfl_xor(ps, d, 64);
      lrow[r] = lrow[r] * alpha[r] + ps;
    }
    {
      f32x4 al = {alpha[0], alpha[1], alpha[2], alpha[3]};
#pragma unroll
      for (int nt = 0; nt < 16; ++nt) yacc[nt] *= al;
    }

    // ---- P: C/D regs -> wave-private LDS in A-frag order (r2 scheme) ----
#pragma unroll
    for (int nv = 0; nv < 8; ++nv) {
      int kq = nv >> 1;
      int lqr = (nv & 1) * 2 + (l15 >> 3);
      int e = l15 & 7;
#pragma unroll
      for (int r = 0; r < 4; ++r) {
        int u = kq * 64 + lqr * 16 + lq * 4 + r;
        Ps[w][u * 8 + e] = (_Float16)S[nv][r];
      }
    }
    f16x8 aP[4];
#pragma unroll
    for (int kq = 0; kq < 4; ++kq)
      aP[kq] = *(const f16x8*)(&Ps[w][(kq * 64 + lane) * 8]);

    // ---- 4 g phases: y += P @ g^T ----
#pragma unroll
    for (int cg = 0; cg < 4; ++cg) {
      if (t == 31 && cg == 3) {
        asm volatile("s_waitcnt vmcnt(0)" ::: "memory");  // final phase: nothing newer in flight
      } else {
        asm volatile("s_waitcnt vmcnt(4)" ::: "memory");
      }
      asm volatile("s_barrier" ::: "memory");
      int bn = bcur + 2; if (bn >= 3) bn -= 3;
      issue(p + 2, bn);
      const _Float16* buf = Stg[bcur];
#pragma unroll
      for (int kq = 0; kq < 4; ++kq)
#pragma unroll
        for (int ct = 0; ct < 4; ++ct) {
          f16x8 bf = *(const f16x8*)(buf + (kq * 256 + ct * 64 + l15 * 4 + lq) * 8);
          yacc[cg * 4 + ct] =
              __builtin_amdgcn_mfma_f32_16x16x32_f16(aP[kq], bf, yacc[cg * 4 + ct], 0, 0, 0);
        }
      ++p; ++bcur; if (bcur == 3) bcur = 0;
    }
  }

  // ---- epilogue: y / l -> yT (wave owns its rows outright) ----
  _Float16* yTb = yT + (long long)b * NN_SP * CI;
#pragma unroll
  for (int r = 0; r < 4; ++r) {
    float inv = 1.f / lrow[r];
    int row = q0 + w * 16 + lq * 4 + r;
#pragma unroll
    for (int nt = 0; nt < 16; ++nt)
      yTb[(long long)row * CI + nt * 16 + l15] = (_Float16)(yacc[nt][r] * inv);
  }
}

extern "C" void kernel_launch(void* const* d_in, const int* in_sizes, int n_in,
                              void* d_out, int out_size, void* d_ws, size_t ws_size,
                              hipStream_t stream) {
  const float* x = (const float*)d_in[0];
  const float* w_phi = (const float*)d_in[1];
  const float* w_theta = (const float*)d_in[2];
  const float* w_g = (const float*)d_in[3];
  const float* w_mask = (const float*)d_in[4];
  float* out = (float*)d_out;
  char* ws = (char*)d_ws;

  // workspace layout (51.4 MB total)
  _Float16* xT = (_Float16*)(ws);                 // (B,4096,512)  16.78 MB
  _Float16* pt = (_Float16*)(ws + 16777216);      // (B,4096,512)  16.78 MB  [phi|theta]
  _Float16* gB = (_Float16*)(ws + 33554432);      // (B,256,4096)   8.39 MB
  _Float16* yT = (_Float16*)(ws + 41943040);      // (B,4096,256)   8.39 MB
  _Float16* wpt = (_Float16*)(ws + 50331648);     // (512,512)
  _Float16* wg = (_Float16*)(ws + 50855936);      // (256,512)
  _Float16* wm = (_Float16*)(ws + 51118080);      // (512,256)

  convert_w<<<2048, 256, 0, stream>>>(w_phi, w_theta, w_g, w_mask, wpt, wg, wm);
  transpose_x<<<dim3(64, 8, 4), 256, 0, stream>>>(x, xT);
  // PT[n, {phi|theta}] = xT @ wpt^T : M=4096, N=512, K=512, per batch
  gemm_bt<4096, 512, 512, true><<<dim3(4, 32, 4), 256, 0, stream>>>(
      xT, wpt, pt, 4096LL * 512, 0, 4096LL * 512);
  // g[c, n] = wg @ x : M=256, N=4096, K=512 (Bt = xT), per batch
  gemm_bt<256, 4096, 512, true><<<dim3(32, 2, 4), 256, 0, stream>>>(
      wg, xT, gB, 0, 4096LL * 512, 256LL * 4096);
  // flash attention v3: 256 blocks, XCD-swizzled
  flash_attn3<<<dim3(256), 256, 0, stream>>>(pt, gB, yT);
  // out[o, n] = wm @ y : M=512, N=4096, K=256 (Bt = yT), fp32 out, per batch
  gemm_bt<512, 4096, 256, false><<<dim3(32, 4, 4), 256, 0, stream>>>(
      wm, yT, out, 0, 4096LL * 256, 512LL * 4096);
}